// Round 1
// baseline (297.695 us; speedup 1.0000x reference)
//
#include <hip/hip_runtime.h>

#define C_CH  256
#define H_FM  200
#define W_FM  200
#define N_BOX 1024
#define OHp   7
#define OWp   7

// ---------------------------------------------------------------------------
// Kernel 1: row-wise inclusive cumsum.  S[c][h][w] = sum_{w'<=w} fm[c][h][w']
// One 256-thread block per (c,h) row (200 elements). Hillis-Steele in LDS.
// ---------------------------------------------------------------------------
__global__ __launch_bounds__(256) void row_scan_kernel(const float* __restrict__ fm,
                                                       float* __restrict__ S) {
    __shared__ float buf[2][256];
    const int row = blockIdx.x;            // c*H_FM + h
    const int t   = threadIdx.x;
    const float* src = fm + (size_t)row * W_FM;
    float v = (t < W_FM) ? src[t] : 0.0f;
    int pin = 0;
    buf[0][t] = v;
    __syncthreads();
    #pragma unroll
    for (int off = 1; off < 256; off <<= 1) {
        float x = buf[pin][t];
        if (t >= off) x += buf[pin][t - off];
        buf[pin ^ 1][t] = x;
        __syncthreads();
        pin ^= 1;
    }
    if (t < W_FM) S[(size_t)row * W_FM + t] = buf[pin][t];
}

// ---------------------------------------------------------------------------
// Kernel 2: column-wise inclusive cumsum, in place.
// One block per channel; thread w owns column w; serial over h (coalesced).
// ---------------------------------------------------------------------------
__global__ __launch_bounds__(256) void col_scan_kernel(float* __restrict__ S) {
    const int c = blockIdx.x;
    const int w = threadIdx.x;
    if (w >= W_FM) return;
    float* p = S + (size_t)c * H_FM * W_FM + w;
    float acc = 0.0f;
    #pragma unroll 4
    for (int h = 0; h < H_FM; ++h) {
        float v = p[(size_t)h * W_FM];
        acc += v;
        p[(size_t)h * W_FM] = acc;
    }
}

// ---------------------------------------------------------------------------
// Shared helper: exact reference bin-edge math.
// ---------------------------------------------------------------------------
__device__ __forceinline__ void box_edges(const float4 box, int i, int j,
                                          int& rs, int& re, int& cs, int& ce) {
    // scale = W/IMG_W = 200/800 = 0.25 exactly
    int b0 = (int)floorf(box.x * 0.25f);
    int b1 = (int)floorf(box.y * 0.25f);
    int b2 = (int)floorf(box.z * 0.25f);
    int b3 = (int)floorf(box.w * 0.25f);
    int x1 = min(max(b0, 0), W_FM - 1);
    int y1 = min(max(b1, 0), H_FM - 1);
    int x2 = min(max(b2 + 1, x1 + 1), W_FM);
    int y2 = min(max(b3 + 1, y1 + 1), H_FM);
    int rh = y2 - y1;
    int rw = x2 - x1;
    rs = y1 + (i * rh) / OHp;
    re = y1 + ((i + 1) * rh + OHp - 1) / OHp;
    cs = x1 + (j * rw) / OWp;
    ce = x1 + ((j + 1) * rw + OWp - 1) / OWp;
}

// ---------------------------------------------------------------------------
// Kernel 3: pooling via 4 integral-image corner lookups per output element.
// One thread per output element (n,c,i,j), j fastest -> coalesced store.
// S is the UNPADDED inclusive 2D cumsum; padded ii(r,k) = (r>0&&k>0) ?
// S[r-1][k-1] : 0.
// ---------------------------------------------------------------------------
__global__ __launch_bounds__(256) void pool_kernel(const float* __restrict__ S,
                                                   const float* __restrict__ boxes,
                                                   float* __restrict__ out) {
    const int idx = blockIdx.x * 256 + threadIdx.x;   // grid sized exactly
    const int j  = idx % OWp;
    const int t1 = idx / OWp;
    const int i  = t1 % OHp;
    const int t2 = t1 / OHp;
    const int c  = t2 % C_CH;
    const int n  = t2 / C_CH;

    const float4 box = ((const float4*)boxes)[n];
    int rs, re, cs, ce;
    box_edges(box, i, j, rs, re, cs, ce);

    const float* Sc = S + (size_t)c * H_FM * W_FM;
    // re >= 1, ce >= 1 always; rs/cs may be 0 (padded border -> 0)
    float a = Sc[(size_t)(re - 1) * W_FM + (ce - 1)];                       // II(re,ce)
    float b = (rs > 0) ? Sc[(size_t)(rs - 1) * W_FM + (ce - 1)] : 0.0f;    // II(rs,ce)
    float d = (cs > 0) ? Sc[(size_t)(re - 1) * W_FM + (cs - 1)] : 0.0f;    // II(re,cs)
    float e = (rs > 0 && cs > 0) ? Sc[(size_t)(rs - 1) * W_FM + (cs - 1)] : 0.0f; // II(rs,cs)

    float total = a - b - d + e;
    float area  = (float)((re - rs) * (ce - cs));
    out[idx] = total / area;
}

// ---------------------------------------------------------------------------
// Fallback: direct region sum (used only if workspace is too small).
// ---------------------------------------------------------------------------
__global__ __launch_bounds__(256) void pool_direct_kernel(const float* __restrict__ fm,
                                                          const float* __restrict__ boxes,
                                                          float* __restrict__ out) {
    const int idx = blockIdx.x * 256 + threadIdx.x;
    const int j  = idx % OWp;
    const int t1 = idx / OWp;
    const int i  = t1 % OHp;
    const int t2 = t1 / OHp;
    const int c  = t2 % C_CH;
    const int n  = t2 / C_CH;

    const float4 box = ((const float4*)boxes)[n];
    int rs, re, cs, ce;
    box_edges(box, i, j, rs, re, cs, ce);

    const float* base = fm + (size_t)c * H_FM * W_FM;
    float sum = 0.0f;
    for (int r = rs; r < re; ++r) {
        const float* rowp = base + (size_t)r * W_FM;
        for (int k = cs; k < ce; ++k) sum += rowp[k];
    }
    float area = (float)((re - rs) * (ce - cs));
    out[idx] = sum / area;
}

// ---------------------------------------------------------------------------
extern "C" void kernel_launch(void* const* d_in, const int* in_sizes, int n_in,
                              void* d_out, int out_size, void* d_ws, size_t ws_size,
                              hipStream_t stream) {
    const float* fm    = (const float*)d_in[0];   // [1,256,200,200] f32
    const float* boxes = (const float*)d_in[1];   // [1024,4] f32
    float* out = (float*)d_out;                   // [1024,256,7,7] f32
    float* S   = (float*)d_ws;

    const size_t need   = (size_t)C_CH * H_FM * W_FM * sizeof(float); // 40.96 MB
    const int    total  = N_BOX * C_CH * OHp * OWp;                   // 12,845,056
    const int    blocks = total / 256;                                // 50,176 exact

    if (ws_size >= need) {
        row_scan_kernel<<<C_CH * H_FM, 256, 0, stream>>>(fm, S);
        col_scan_kernel<<<C_CH, 256, 0, stream>>>(S);
        pool_kernel<<<blocks, 256, 0, stream>>>(S, boxes, out);
    } else {
        pool_direct_kernel<<<blocks, 256, 0, stream>>>(fm, boxes, out);
    }
}

// Round 2
// 181.819 us; speedup vs baseline: 1.6373x; 1.6373x over previous
//
#include <hip/hip_runtime.h>

#define C_CH  256
#define H_FM  200
#define W_FM  200
#define N_BOX 1024
#define OHp   7
#define OWp   7
#define WC    (W_FM * C_CH)          // 51200 floats per h-row of T
#define NCHUNK 25                    // h chunks of 8 rows
#define CHROWS 8

// ============================================================================
// NEW PATH: channel-last integral image T[h][w][c]
// ============================================================================

// ---------------------------------------------------------------------------
// K1: row-wise inclusive cumsum of fm[c][h][w] over w, written TRANSPOSED to
// T[h][w][c]. Block = (c-tile of 64, one h). LDS tile 64x201 (padded).
// ---------------------------------------------------------------------------
__global__ __launch_bounds__(256) void rowscan_transpose_kernel(const float* __restrict__ fm,
                                                                float* __restrict__ T) {
    __shared__ float lds[64][201];   // +1 pad breaks transpose-read conflicts
    const int t  = threadIdx.x;
    const int c0 = blockIdx.x * 64;
    const int h  = blockIdx.y;

    // Load 64 channel-rows of 200 floats (coalesced in 200-float runs).
    const float* src = fm + (size_t)c0 * (H_FM * W_FM) + (size_t)h * W_FM;
    #pragma unroll 10
    for (int m = 0; m < 50; ++m) {
        int flat = m * 256 + t;          // 0..12799
        int ci = flat / 200;
        int w  = flat - ci * 200;
        lds[ci][w] = src[(size_t)ci * (H_FM * W_FM) + w];
    }
    __syncthreads();

    // Wave shuffle inclusive scan: wave wv owns rows [wv*16, wv*16+16).
    const int lane = t & 63;
    const int wv   = t >> 6;
    for (int r = wv * 16; r < wv * 16 + 16; ++r) {
        float carry = 0.0f;
        #pragma unroll
        for (int seg = 0; seg < 4; ++seg) {
            int idx = seg * 64 + lane;
            float v = (idx < W_FM) ? lds[r][idx] : 0.0f;
            #pragma unroll
            for (int off = 1; off < 64; off <<= 1) {
                float y = __shfl_up(v, off, 64);
                if (lane >= off) v += y;
            }
            v += carry;
            if (idx < W_FM) lds[r][idx] = v;
            carry = __shfl(v, 63, 64);
        }
    }
    __syncthreads();

    // Transposed store: T[h][w][c0+c_off], coalesced over c.
    const int c_off = t & 63;
    const int q     = t >> 6;
    float* dst = T + (size_t)h * WC + c0 + c_off;
    #pragma unroll 10
    for (int m = 0; m < 50; ++m) {
        int w = 4 * m + q;
        dst[(size_t)w * C_CH] = lds[c_off][w];
    }
}

// ---------------------------------------------------------------------------
// K2: column cumsum over h, per chunk of 8 rows, in place on T[h][w][c].
// Fully coalesced. Writes chunk totals to aux[ch][w][c].
// ---------------------------------------------------------------------------
__global__ __launch_bounds__(256) void colscan_chunk_kernel(float* __restrict__ T,
                                                            float* __restrict__ aux) {
    const int wc = blockIdx.x * 256 + threadIdx.x;   // 0..WC-1
    const int ch = blockIdx.y;                        // 0..NCHUNK-1
    float* p = T + (size_t)(ch * CHROWS) * WC + wc;
    float acc = 0.0f;
    #pragma unroll
    for (int k = 0; k < CHROWS; ++k) {
        acc += p[(size_t)k * WC];
        p[(size_t)k * WC] = acc;
    }
    aux[(size_t)ch * WC + wc] = acc;
}

// ---------------------------------------------------------------------------
// K3: exclusive scan of chunk totals over the 25 chunks, in place.
// ---------------------------------------------------------------------------
__global__ __launch_bounds__(256) void aux_scan_kernel(float* __restrict__ aux) {
    const int wc = blockIdx.x * 256 + threadIdx.x;
    float acc = 0.0f;
    #pragma unroll
    for (int ch = 0; ch < NCHUNK; ++ch) {
        float v = aux[(size_t)ch * WC + wc];
        aux[(size_t)ch * WC + wc] = acc;
        acc += v;
    }
}

// ---------------------------------------------------------------------------
// K4: T[h][w][c] += aux[ch(h)][w][c], float4-vectorized. Chunk 0 (offsets
// all zero) is skipped: element offset starts at h=8.
// ---------------------------------------------------------------------------
__global__ __launch_bounds__(256) void add_offsets_kernel(float* __restrict__ T,
                                                          const float* __restrict__ aux) {
    const int idx = (CHROWS * WC / 4) + blockIdx.x * 256 + threadIdx.x; // skip chunk 0
    const int h = idx / (WC / 4);
    const int q = idx - h * (WC / 4);
    const int ch = h >> 3;
    const float4 o = ((const float4*)aux)[(size_t)ch * (WC / 4) + q];
    float4* tp = (float4*)T + (size_t)h * (WC / 4) + q;
    float4 v = *tp;
    v.x += o.x; v.y += o.y; v.z += o.z; v.w += o.w;
    *tp = v;
}

// ---------------------------------------------------------------------------
// K5: pooling. Block = one box, thread = one channel. All II corner reads are
// coalesced 1 KB transactions (contiguous over c). Output staged in LDS and
// flushed coalesced.
// II(r,k) with zero pad: r,k in [0,200]; = T[(r-1)*200+(k-1)][c] when r,k>=1.
// ---------------------------------------------------------------------------
__global__ __launch_bounds__(256) void pool2_kernel(const float* __restrict__ T,
                                                    const float* __restrict__ boxes,
                                                    float* __restrict__ out) {
    __shared__ float lo[256 * 50];   // [c][49] padded to 50
    const int n = blockIdx.x;
    const int c = threadIdx.x;

    const float4 box = ((const float4*)boxes)[n];
    int b0 = (int)floorf(box.x * 0.25f);
    int b1 = (int)floorf(box.y * 0.25f);
    int b2 = (int)floorf(box.z * 0.25f);
    int b3 = (int)floorf(box.w * 0.25f);
    int x1 = min(max(b0, 0), W_FM - 1);
    int y1 = min(max(b1, 0), H_FM - 1);
    int x2 = min(max(b2 + 1, x1 + 1), W_FM);
    int y2 = min(max(b3 + 1, y1 + 1), H_FM);
    int rh = y2 - y1;
    int rw = x2 - x1;

    int rs[OHp], re[OHp], cols[2 * OWp];
    #pragma unroll
    for (int i = 0; i < OHp; ++i) {
        rs[i] = y1 + (i * rh) / OHp;
        re[i] = y1 + ((i + 1) * rh + OHp - 1) / OHp;
    }
    #pragma unroll
    for (int j = 0; j < OWp; ++j) {
        cols[j]       = x1 + (j * rw) / OWp;              // cs_j
        cols[OWp + j] = x1 + ((j + 1) * rw + OWp - 1) / OWp; // ce_j
    }

    const float* Tc = T + c;
    #pragma unroll
    for (int i = 0; i < OHp; ++i) {
        float top[2 * OWp], bot[2 * OWp];
        const int rt = rs[i], rb = re[i];
        #pragma unroll
        for (int k = 0; k < 2 * OWp; ++k) {
            const int kk = cols[k];
            // block-uniform conditions -> no divergence
            top[k] = (rt > 0 && kk > 0) ? Tc[((size_t)(rt - 1) * W_FM + (kk - 1)) * C_CH] : 0.0f;
            bot[k] = (kk > 0)           ? Tc[((size_t)(rb - 1) * W_FM + (kk - 1)) * C_CH] : 0.0f;
        }
        const float rowspan = (float)(rb - rt);
        #pragma unroll
        for (int j = 0; j < OWp; ++j) {
            float total = (bot[OWp + j] - bot[j]) - (top[OWp + j] - top[j]);
            float area  = rowspan * (float)(cols[OWp + j] - cols[j]);
            lo[c * 50 + i * OWp + j] = total / area;
        }
    }
    __syncthreads();

    // Coalesced flush: out[n][c][i][j], flat = c*49 + i*7 + j
    float* dst = out + (size_t)n * (C_CH * OHp * OWp);
    #pragma unroll 7
    for (int m = 0; m < 49; ++m) {
        int flat = m * 256 + c;
        int cc = flat / 49;
        int ii = flat - cc * 49;
        dst[flat] = lo[cc * 50 + ii];
    }
}

// ============================================================================
// FALLBACK PATH (Round-1 kernels) — used only if workspace is too small.
// ============================================================================
__global__ __launch_bounds__(256) void row_scan_kernel(const float* __restrict__ fm,
                                                       float* __restrict__ S) {
    __shared__ float buf[2][256];
    const int row = blockIdx.x;
    const int t   = threadIdx.x;
    const float* src = fm + (size_t)row * W_FM;
    float v = (t < W_FM) ? src[t] : 0.0f;
    int pin = 0;
    buf[0][t] = v;
    __syncthreads();
    #pragma unroll
    for (int off = 1; off < 256; off <<= 1) {
        float x = buf[pin][t];
        if (t >= off) x += buf[pin][t - off];
        buf[pin ^ 1][t] = x;
        __syncthreads();
        pin ^= 1;
    }
    if (t < W_FM) S[(size_t)row * W_FM + t] = buf[pin][t];
}

__global__ __launch_bounds__(256) void col_scan_kernel(float* __restrict__ S) {
    const int c = blockIdx.x;
    const int w = threadIdx.x;
    if (w >= W_FM) return;
    float* p = S + (size_t)c * H_FM * W_FM + w;
    float acc = 0.0f;
    #pragma unroll 4
    for (int h = 0; h < H_FM; ++h) {
        float v = p[(size_t)h * W_FM];
        acc += v;
        p[(size_t)h * W_FM] = acc;
    }
}

__device__ __forceinline__ void box_edges(const float4 box, int i, int j,
                                          int& rs, int& re, int& cs, int& ce) {
    int b0 = (int)floorf(box.x * 0.25f);
    int b1 = (int)floorf(box.y * 0.25f);
    int b2 = (int)floorf(box.z * 0.25f);
    int b3 = (int)floorf(box.w * 0.25f);
    int x1 = min(max(b0, 0), W_FM - 1);
    int y1 = min(max(b1, 0), H_FM - 1);
    int x2 = min(max(b2 + 1, x1 + 1), W_FM);
    int y2 = min(max(b3 + 1, y1 + 1), H_FM);
    int rh = y2 - y1;
    int rw = x2 - x1;
    rs = y1 + (i * rh) / OHp;
    re = y1 + ((i + 1) * rh + OHp - 1) / OHp;
    cs = x1 + (j * rw) / OWp;
    ce = x1 + ((j + 1) * rw + OWp - 1) / OWp;
}

__global__ __launch_bounds__(256) void pool_kernel(const float* __restrict__ S,
                                                   const float* __restrict__ boxes,
                                                   float* __restrict__ out) {
    const int idx = blockIdx.x * 256 + threadIdx.x;
    const int j  = idx % OWp;
    const int t1 = idx / OWp;
    const int i  = t1 % OHp;
    const int t2 = t1 / OHp;
    const int c  = t2 % C_CH;
    const int n  = t2 / C_CH;

    const float4 box = ((const float4*)boxes)[n];
    int rs, re, cs, ce;
    box_edges(box, i, j, rs, re, cs, ce);

    const float* Sc = S + (size_t)c * H_FM * W_FM;
    float a = Sc[(size_t)(re - 1) * W_FM + (ce - 1)];
    float b = (rs > 0) ? Sc[(size_t)(rs - 1) * W_FM + (ce - 1)] : 0.0f;
    float d = (cs > 0) ? Sc[(size_t)(re - 1) * W_FM + (cs - 1)] : 0.0f;
    float e = (rs > 0 && cs > 0) ? Sc[(size_t)(rs - 1) * W_FM + (cs - 1)] : 0.0f;

    float total = a - b - d + e;
    float area  = (float)((re - rs) * (ce - cs));
    out[idx] = total / area;
}

__global__ __launch_bounds__(256) void pool_direct_kernel(const float* __restrict__ fm,
                                                          const float* __restrict__ boxes,
                                                          float* __restrict__ out) {
    const int idx = blockIdx.x * 256 + threadIdx.x;
    const int j  = idx % OWp;
    const int t1 = idx / OWp;
    const int i  = t1 % OHp;
    const int t2 = t1 / OHp;
    const int c  = t2 % C_CH;
    const int n  = t2 / C_CH;

    const float4 box = ((const float4*)boxes)[n];
    int rs, re, cs, ce;
    box_edges(box, i, j, rs, re, cs, ce);

    const float* base = fm + (size_t)c * H_FM * W_FM;
    float sum = 0.0f;
    for (int r = rs; r < re; ++r) {
        const float* rowp = base + (size_t)r * W_FM;
        for (int k = cs; k < ce; ++k) sum += rowp[k];
    }
    float area = (float)((re - rs) * (ce - cs));
    out[idx] = sum / area;
}

// ---------------------------------------------------------------------------
extern "C" void kernel_launch(void* const* d_in, const int* in_sizes, int n_in,
                              void* d_out, int out_size, void* d_ws, size_t ws_size,
                              hipStream_t stream) {
    const float* fm    = (const float*)d_in[0];   // [1,256,200,200] f32
    const float* boxes = (const float*)d_in[1];   // [1024,4] f32
    float* out = (float*)d_out;                   // [1024,256,7,7] f32

    const size_t tBytes   = (size_t)H_FM * WC * sizeof(float);        // 40.96 MB
    const size_t auxBytes = (size_t)NCHUNK * WC * sizeof(float);      // 5.12 MB
    const int    total    = N_BOX * C_CH * OHp * OWp;
    const int    blocks   = total / 256;

    if (ws_size >= tBytes + auxBytes) {
        float* T   = (float*)d_ws;
        float* aux = (float*)((char*)d_ws + tBytes);
        rowscan_transpose_kernel<<<dim3(C_CH / 64, H_FM), 256, 0, stream>>>(fm, T);
        colscan_chunk_kernel<<<dim3(WC / 256, NCHUNK), 256, 0, stream>>>(T, aux);
        aux_scan_kernel<<<WC / 256, 256, 0, stream>>>(aux);
        add_offsets_kernel<<<(H_FM - CHROWS) * (WC / 4) / 256, 256, 0, stream>>>(T, aux);
        pool2_kernel<<<N_BOX, 256, 0, stream>>>(T, boxes, out);
    } else if (ws_size >= tBytes) {
        float* S = (float*)d_ws;
        row_scan_kernel<<<C_CH * H_FM, 256, 0, stream>>>(fm, S);
        col_scan_kernel<<<C_CH, 256, 0, stream>>>(S);
        pool_kernel<<<blocks, 256, 0, stream>>>(S, boxes, out);
    } else {
        pool_direct_kernel<<<blocks, 256, 0, stream>>>(fm, boxes, out);
    }
}